// Round 6
// baseline (181.015 us; speedup 1.0000x reference)
//
#include <hip/hip_runtime.h>

typedef unsigned short u16;
typedef unsigned int   u32;
typedef unsigned long long u64;

typedef __attribute__((ext_vector_type(8))) short bf16x8;
typedef __attribute__((ext_vector_type(4))) float f32x4;
typedef __attribute__((ext_vector_type(2))) float f32x2;

#define BB 4
#define MM 2048
#define NN 16384
#define DD 64

__device__ __forceinline__ u16 f2bf(float f) {
    union { float f; u32 u; } v; v.f = f;
    u32 r = v.u + 0x7fffu + ((v.u >> 16) & 1u);   // RNE
    return (u16)(r >> 16);
}

// pack two floats to bf16 pair by truncation: lo16=trunc(lo), hi16=trunc(hi)
__device__ __forceinline__ u32 pack_trunc(float hi, float lo) {
    union { float f; u32 u; } a, b; a.f = hi; b.f = lo;
    return __builtin_amdgcn_perm(a.u, b.u, 0x07060302);
}

// RNE pack of two floats into a bf16 pair
__device__ __forceinline__ u32 pack_rne(float hi, float lo) {
    return (u32)f2bf(lo) | ((u32)f2bf(hi) << 16);
}

__device__ __forceinline__ bf16x8 pack8(float4 p, float4 q) {
    bf16x8 v;
    v[0] = (short)f2bf(p.x); v[1] = (short)f2bf(p.y);
    v[2] = (short)f2bf(p.z); v[3] = (short)f2bf(p.w);
    v[4] = (short)f2bf(q.x); v[5] = (short)f2bf(q.y);
    v[6] = (short)f2bf(q.z); v[7] = (short)f2bf(q.w);
    return v;
}

// ===========================================================================
// ws layout (v6 path):
//   [0, 1M)      fdT  bf16 [b][d][m]        (feat_down transposed)
//   [1M, +128K)  xyzP pair-SoA: per pair {-2x0,-2x1,-2y0,-2y1}{-2z0,-2z1,w0,w1}
//   [.., +32K)   w1s  bf16 frag-major [kg*8+ot][lane][8]
//   [.., +16K)   w2s  bf16 frag-major [kg*4+ot][lane][8]
//   [.., +1.5K)  bn consts float[384] = A1[128] Bc1[128] A2[64] Bc2[64]
// ===========================================================================
#define OFF_FDT   0ull
#define OFF_XYZP  1048576ull
#define OFF_W1S   1179648ull
#define OFF_W2S   1212416ull
#define OFF_BN    1228800ull
#define WS_NEED   1230336ull

// ---------------------------------------------------------------------------
// prep5: 157 blocks x 256.
//  blk   0..127 : feat_down transpose -> fdT   (proven prep4 code)
//  blk 128..143 : xyzP pair-SoA
//  blk 144..151 : W1 -> bf16 frag-major
//  blk 152..155 : W2 -> bf16 frag-major
//  blk 156      : BN fold
// ---------------------------------------------------------------------------
__global__ __launch_bounds__(256)
void prep5_kernel(const float* __restrict__ xyz_down,
                  const float* __restrict__ feat_down,
                  const float* __restrict__ W1, const float* __restrict__ b1,
                  const float* __restrict__ g1, const float* __restrict__ be1,
                  const float* __restrict__ m1, const float* __restrict__ v1,
                  const float* __restrict__ W2, const float* __restrict__ b2,
                  const float* __restrict__ g2, const float* __restrict__ be2,
                  const float* __restrict__ m2, const float* __restrict__ v2,
                  u16* __restrict__ fdT, float4* __restrict__ xyzP,
                  u16* __restrict__ w1s, u16* __restrict__ w2s,
                  float* __restrict__ bnbuf)
{
    const int blk = blockIdx.x, t = threadIdx.x;
    if (blk < 128) {
        __shared__ u16 T[64 * 70];                 // [m_local][d], stride 70
        const int b = blk >> 5, m0 = (blk & 31) * 64;
        {
            const int row = t >> 2, fcb = (t & 3) * 16;
            const float4* src = (const float4*)(feat_down + ((size_t)(b * MM + m0 + row)) * 64 + fcb);
#pragma unroll
            for (int i = 0; i < 4; i++) {
                float4 v = src[i];
                union { u16 h[4]; u64 q; } pk;
                pk.h[0] = f2bf(v.x); pk.h[1] = f2bf(v.y);
                pk.h[2] = f2bf(v.z); pk.h[3] = f2bf(v.w);
                *(u64*)&T[row * 70 + fcb + i * 4] = pk.q;
            }
        }
        __syncthreads();
        {
            const int d = t & 63, w = t >> 6;
            union { u16 h[16]; uint4 q[2]; } o;
#pragma unroll
            for (int j = 0; j < 16; j++) o.h[j] = T[(w * 16 + j) * 70 + d];
            uint4* dst = (uint4*)&fdT[((size_t)(b * 64 + d)) * MM + m0 + w * 16];
            dst[0] = o.q[0];
            dst[1] = o.q[1];
        }
    } else if (blk < 144) {
        int g = (blk - 128) * 256 + t;             // pair index over 4096
        int b = g >> 10, p = g & 1023;
        const float* s = xyz_down + ((size_t)b * MM + 2 * p) * 3;
        float x0 = s[0], y0 = s[1], z0 = s[2];
        float x1 = s[3], y1 = s[4], z1 = s[5];
        float w0 = x0 * x0 + y0 * y0 + z0 * z0 + 1e-8f;
        float w1v = x1 * x1 + y1 * y1 + z1 * z1 + 1e-8f;
        xyzP[(size_t)g * 2 + 0] = make_float4(-2.f * x0, -2.f * x1, -2.f * y0, -2.f * y1);
        xyzP[(size_t)g * 2 + 1] = make_float4(-2.f * z0, -2.f * z1, w0, w1v);
    } else if (blk < 152) {
        int slot = (blk - 144) * 256 + t;          // 0..2047
        int f = slot >> 6, l = slot & 63;
        int kg = f >> 3, ot = f & 7;
        int o = ot * 16 + (l & 15), c = kg * 32 + (l >> 4) * 8;
        const float4* src = (const float4*)(W1 + (size_t)o * 128 + c);
        bf16x8 v = pack8(src[0], src[1]);
        *(bf16x8*)&w1s[(size_t)slot * 8] = v;
    } else if (blk < 156) {
        int slot = (blk - 152) * 256 + t;          // 0..1023
        int f = slot >> 6, l = slot & 63;
        int kg = f >> 2, ot = f & 3;
        int o = ot * 16 + (l & 15), c = kg * 32 + (l >> 4) * 8;
        const float4* src = (const float4*)(W2 + (size_t)o * 128 + c);
        bf16x8 v = pack8(src[0], src[1]);
        *(bf16x8*)&w2s[(size_t)slot * 8] = v;
    } else {
        if (t < 128) {
            float a = g1[t] * rsqrtf(v1[t] + 1e-5f);
            bnbuf[t] = a;
            bnbuf[128 + t] = (b1[t] - m1[t]) * a + be1[t];
        } else if (t < 192) {
            int o = t - 128;
            float a = g2[o] * rsqrtf(v2[o] + 1e-5f);
            bnbuf[256 + o] = a;
            bnbuf[320 + o] = (b2[o] - m2[o]) * a + be2[o];
        }
    }
}

// ---------------------------------------------------------------------------
// fused6: interp (LDS-dbuf ftbuf, xyz via broadcast VMEM, packed fp32,
// den via MFMA-ones) + MLP (A-frags via LDS transpose, B-frags = frag-major
// coalesced global weight reads) + coalesced f32 out stores.
// 1024 blocks x 256; LDS 37.4 KB -> 4 blocks/CU.
// ---------------------------------------------------------------------------
__global__ __launch_bounds__(256, 4)
void fused6_kernel(const float* __restrict__ xyz_up,
                   const u16* __restrict__ fdT,
                   const float4* __restrict__ xyzP,
                   const float* __restrict__ feat_up,
                   const u16* __restrict__ w1s,
                   const u16* __restrict__ w2s,
                   const float* __restrict__ bnbuf,
                   float* __restrict__ out)
{
    __shared__ u16   ftbuf[2][64 * 72];   // 18432 B
    __shared__ u16   xh[64 * 136];        // 17408 B (x, then h, then f32 out @ stride 68 dw)
    __shared__ float bnl[384];            //  1536 B

    const int tid = threadIdx.x;
    const int b  = blockIdx.x >> 8;
    const int n0 = (blockIdx.x & 255) * 64;
    const int wave = tid >> 6;
    const int lane = tid & 63;
    const int q    = lane >> 4;
    const int nl   = lane & 15;

    bnl[tid] = bnbuf[tid];
    if (tid < 128) bnl[256 + tid] = bnbuf[256 + tid];

    // stage feat_up -> xh cols 0..63 (coalesced; wave-private rows tid>>2)
    {
        const int r = tid >> 2, seg = (tid & 3) * 16;
        const float4* fs = (const float4*)(feat_up + ((size_t)(b * NN + n0 + r)) * 64 + seg);
        float4 f0 = fs[0], f1 = fs[1], f2 = fs[2], f3 = fs[3];
        uint4 o0, o1;
        o0.x = pack_rne(f0.y, f0.x); o0.y = pack_rne(f0.w, f0.z);
        o0.z = pack_rne(f1.y, f1.x); o0.w = pack_rne(f1.w, f1.z);
        o1.x = pack_rne(f2.y, f2.x); o1.y = pack_rne(f2.w, f2.z);
        o1.z = pack_rne(f3.y, f3.x); o1.w = pack_rne(f3.w, f3.z);
        uint4* xd = (uint4*)&xh[r * 136 + seg];
        xd[0] = o0; xd[1] = o1;
    }

    // ---------------- interp phase ----------------
    const int row = n0 + wave * 16 + nl;
    const float* xu = xyz_up + ((size_t)(b * NN + row)) * 3;
    const float ax = xu[0], ay = xu[1], az = xu[2];
    const f32x2 ax2 = (f32x2){ax, ax}, ay2 = (f32x2){ay, ay}, az2 = (f32x2){az, az};
    const f32x2 a22 = (f32x2){ax * ax + ay * ay + az * az,
                              ax * ax + ay * ay + az * az};
    const f32x2 eps2 = (f32x2){1e-8f, 1e-8f};

    f32x4 acc[4];
#pragma unroll
    for (int i = 0; i < 4; i++) acc[i] = (f32x4){0.f, 0.f, 0.f, 0.f};
    f32x4 accd = (f32x4){0.f, 0.f, 0.f, 0.f};

    bf16x8 ones;
#pragma unroll
    for (int i = 0; i < 8; i++) ones[i] = (short)0x3F80;   // bf16 1.0

    // ftbuf staging identity: thread covers (d = tid>>2, 32B of m)
    const int sd = tid >> 2, sms = (tid & 3) * 16;
    const u16* fsrc = fdT + ((size_t)(b * 64 + sd)) * MM + sms;
    const float4* xb = xyzP + (size_t)b * 2048;   // 1024 pairs x 2 float4

    {   // prologue: stage chunk 0
        u16* fd = &ftbuf[0][sd * 72 + sms];
        *(uint4*)fd       = *(const uint4*)(fsrc);
        *(uint4*)(fd + 8) = *(const uint4*)(fsrc + 8);
    }
    __syncthreads();

    for (int c = 0; c < 32; ++c) {
        const int cur = c & 1, nxt = cur ^ 1;
        const bool have_next = (c + 1) < 32;
        uint4 nf0, nf1;
        if (have_next) {
            const int mc = (c + 1) * 64;
            nf0 = *(const uint4*)(fsrc + mc);
            nf1 = *(const uint4*)(fsrc + mc + 8);
        }

#pragma unroll
        for (int kk = 0; kk < 2; kk++) {
            u32 fr[4];
#pragma unroll
            for (int jp = 0; jp < 4; jp++) {
                // pair index: broadcast VMEM read (16-lane-uniform address, L1)
                const float4* pp = xb + (size_t)(c * 32 + kk * 16 + q * 4 + jp) * 2;
                float4 ld0 = pp[0];                // {-2x0,-2x1,-2y0,-2y1}
                float4 ld1 = pp[1];                // {-2z0,-2z1, w0, w1}
                f32x2 px = (f32x2){ld0.x, ld0.y};
                f32x2 py = (f32x2){ld0.z, ld0.w};
                f32x2 pz = (f32x2){ld1.x, ld1.y};
                f32x2 pw = (f32x2){ld1.z, ld1.w};
                f32x2 d = __builtin_elementwise_fma(px, ax2,
                          __builtin_elementwise_fma(py, ay2,
                          __builtin_elementwise_fma(pz, az2, pw + a22)));
                d = __builtin_elementwise_max(d, eps2);
                float r0 = __builtin_amdgcn_rcpf(d.x);
                float r1 = __builtin_amdgcn_rcpf(d.y);
                fr[jp] = pack_trunc(r1, r0);
            }
            union { u32 u[4]; bf16x8 v; } af;
            af.u[0] = fr[0]; af.u[1] = fr[1]; af.u[2] = fr[2]; af.u[3] = fr[3];
#pragma unroll
            for (int dt = 0; dt < 4; dt++) {
                bf16x8 bb = *(bf16x8*)&ftbuf[cur][(dt * 16 + nl) * 72 + kk * 32 + q * 8];
                acc[dt] = __builtin_amdgcn_mfma_f32_16x16x32_bf16(af.v, bb, acc[dt], 0, 0, 0);
            }
            // den from the SAME truncated r (ones B-frag) -> bias cancels
            accd = __builtin_amdgcn_mfma_f32_16x16x32_bf16(af.v, ones, accd, 0, 0, 0);
        }

        if (have_next) {
            u16* fd = &ftbuf[nxt][sd * 72 + sms];
            *(uint4*)fd       = nf0;
            *(uint4*)(fd + 8) = nf1;
        }
        __syncthreads();
    }

    // interp epilogue: normalize, write bf16 into xh cols 64..127
    // (wave-private rows wave*16+q*4+reg)
#pragma unroll
    for (int reg = 0; reg < 4; reg++) {
        float inv = 1.0f / accd[reg];
        int rl = wave * 16 + q * 4 + reg;
#pragma unroll
        for (int dt = 0; dt < 4; dt++)
            xh[rl * 136 + 64 + dt * 16 + nl] = f2bf(acc[dt][reg] * inv);
    }
    __syncthreads();

    // ---------------- GEMM1: x(64x128) @ W1^T -> h(64x128) ----------------
    f32x4 acc1[8];
#pragma unroll
    for (int i = 0; i < 8; i++) acc1[i] = (f32x4){0.f, 0.f, 0.f, 0.f};
#pragma unroll
    for (int kg = 0; kg < 4; kg++) {
        bf16x8 af = *(bf16x8*)&xh[(wave * 16 + nl) * 136 + kg * 32 + q * 8];
#pragma unroll
        for (int ot = 0; ot < 8; ot++) {
            // frag-major coalesced: 64 lanes x 16B contiguous
            bf16x8 bf = *(const bf16x8*)(w1s + ((size_t)(kg * 8 + ot) * 64 + lane) * 8);
            acc1[ot] = __builtin_amdgcn_mfma_f32_16x16x32_bf16(af, bf, acc1[ot], 0, 0, 0);
        }
    }
    // BN1 + ReLU -> bf16 h into xh (wave-private rows)
#pragma unroll
    for (int ot = 0; ot < 8; ot++) {
        int o = ot * 16 + nl;
        float aa = bnl[o], bc = bnl[128 + o];
#pragma unroll
        for (int reg = 0; reg < 4; reg++) {
            float v = fmaxf(fmaf(acc1[ot][reg], aa, bc), 0.f);
            xh[(wave * 16 + q * 4 + reg) * 136 + o] = f2bf(v);
        }
    }
    __syncthreads();

    // ---------------- GEMM2: h(64x128) @ W2^T -> out(64x64) ----------------
    f32x4 acc2[4];
#pragma unroll
    for (int i = 0; i < 4; i++) acc2[i] = (f32x4){0.f, 0.f, 0.f, 0.f};
#pragma unroll
    for (int kg = 0; kg < 4; kg++) {
        bf16x8 af = *(bf16x8*)&xh[(wave * 16 + nl) * 136 + kg * 32 + q * 8];
#pragma unroll
        for (int ot = 0; ot < 4; ot++) {
            bf16x8 bf = *(const bf16x8*)(w2s + ((size_t)(kg * 4 + ot) * 64 + lane) * 8);
            acc2[ot] = __builtin_amdgcn_mfma_f32_16x16x32_bf16(af, bf, acc2[ot], 0, 0, 0);
        }
    }
    // BN2 -> f32 tile in xh (float view stride 68 dw = same 272B rows ->
    // wave-private slab; own h reads complete in-order before these writes)
    float* of = (float*)xh;
#pragma unroll
    for (int ot = 0; ot < 4; ot++) {
        int o = ot * 16 + nl;
        float aa = bnl[256 + o], bc = bnl[320 + o];
#pragma unroll
        for (int reg = 0; reg < 4; reg++)
            of[(wave * 16 + q * 4 + reg) * 68 + o] = fmaf(acc2[ot][reg], aa, bc);
    }
    __syncthreads();

    // coalesced out store
    {
        const int r = tid >> 2, seg = (tid & 3) * 16;
        const float4* sf = (const float4*)&of[r * 68 + seg];
        float4* dst = (float4*)(out + ((size_t)(b * NN + n0 + r)) * 64 + seg);
#pragma unroll
        for (int i = 0; i < 4; i++) dst[i] = sf[i];
    }
}

// ===========================================================================
// Fallback (round-1 kernels, proven): used when ws_size < WS_NEED.
// ===========================================================================
#define TN 128
#define BM 64
#define RS 72
#define FS 72

__global__ __launch_bounds__(256, 3)
void interp_kernel(const float* __restrict__ xyz_down,
                   const float* __restrict__ xyz_up,
                   const float* __restrict__ feat_down,
                   u16* __restrict__ interp_out)
{
    __shared__ u16   rbuf[TN * RS];
    __shared__ u16   ftbuf[DD * FS];
    __shared__ float xyzb[BM * 3];
    __shared__ float denp[TN * 2];
    __shared__ float invden[TN];

    const int tid = threadIdx.x;
    const int b  = blockIdx.x >> 7;
    const int n0 = (blockIdx.x & 127) * TN;

    const int nl_r = tid >> 1;
    const int half = tid & 1;
    const float* xu = xyz_up + (size_t)(b * NN + n0 + nl_r) * 3;
    const float ax = xu[0], ay = xu[1], az = xu[2];

    denp[tid] = 0.f;

    const int wave = tid >> 6;
    const int lane = tid & 63;
    const int q    = lane >> 4;
    const int nl   = lane & 15;

    f32x4 acc[2][4];
#pragma unroll
    for (int i = 0; i < 2; i++)
#pragma unroll
        for (int j = 0; j < 4; j++) acc[i][j] = (f32x4){0.f, 0.f, 0.f, 0.f};

    const int sm = (tid & 31) * 2;
    const int sd = (tid >> 5) * 8;

    for (int mc = 0; mc < MM; mc += BM) {
        __syncthreads();
        if (tid < 192) xyzb[tid] = xyz_down[(size_t)(b * MM + mc) * 3 + tid];
        {
            const float4* f0 = (const float4*)(feat_down + (size_t)(b * MM + mc + sm) * DD + sd);
            const float4* f1 = (const float4*)(feat_down + (size_t)(b * MM + mc + sm + 1) * DD + sd);
            float4 a0 = f0[0], a1 = f0[1];
            float4 b0 = f1[0], b1 = f1[1];
            float r0[8] = {a0.x, a0.y, a0.z, a0.w, a1.x, a1.y, a1.z, a1.w};
            float r1[8] = {b0.x, b0.y, b0.z, b0.w, b1.x, b1.y, b1.z, b1.w};
#pragma unroll
            for (int j = 0; j < 8; j++) {
                u32 pk = (u32)f2bf(r0[j]) | ((u32)f2bf(r1[j]) << 16);
                *(u32*)&ftbuf[(sd + j) * FS + sm] = pk;
            }
        }
        __syncthreads();
        {
            float dlc = 0.f;
#pragma unroll
            for (int s = 0; s < 4; s++) {
                bf16x8 v;
#pragma unroll
                for (int j = 0; j < 8; j++) {
                    int m = half * 32 + s * 8 + j;
                    float dx = ax - xyzb[3 * m + 0];
                    float dy = ay - xyzb[3 * m + 1];
                    float dz = az - xyzb[3 * m + 2];
                    float d = fmaf(dx, dx, fmaf(dy, dy, dz * dz)) + 1e-8f;
                    float r = __builtin_amdgcn_rcpf(d);
                    dlc += r;
                    v[j] = (short)f2bf(r);
                }
                *(bf16x8*)&rbuf[nl_r * RS + half * 32 + s * 8] = v;
            }
            denp[nl_r * 2 + half] += dlc;
        }
        __syncthreads();
        {
            const int rowbase = wave * 32;
#pragma unroll
            for (int k0 = 0; k0 < BM; k0 += 32) {
                bf16x8 a0 = *(bf16x8*)&rbuf[(rowbase + nl) * RS + k0 + q * 8];
                bf16x8 a1 = *(bf16x8*)&rbuf[(rowbase + 16 + nl) * RS + k0 + q * 8];
#pragma unroll
                for (int dt = 0; dt < 4; dt++) {
                    bf16x8 bb = *(bf16x8*)&ftbuf[(dt * 16 + nl) * FS + k0 + q * 8];
                    acc[0][dt] = __builtin_amdgcn_mfma_f32_16x16x32_bf16(a0, bb, acc[0][dt], 0, 0, 0);
                    acc[1][dt] = __builtin_amdgcn_mfma_f32_16x16x32_bf16(a1, bb, acc[1][dt], 0, 0, 0);
                }
            }
        }
    }

    __syncthreads();
    if (tid < TN) invden[tid] = 1.0f / (denp[tid * 2] + denp[tid * 2 + 1]);
    __syncthreads();
    {
        const int rowbase = wave * 32;
#pragma unroll
        for (int nt = 0; nt < 2; nt++) {
#pragma unroll
            for (int reg = 0; reg < 4; reg++) {
                int nloc = rowbase + nt * 16 + q * 4 + reg;
                float inv = invden[nloc];
                size_t gbase = (size_t)(b * NN + n0 + nloc) * DD;
#pragma unroll
                for (int dt = 0; dt < 4; dt++)
                    interp_out[gbase + dt * 16 + nl] = f2bf(acc[nt][dt][reg] * inv);
            }
        }
    }
}

#define T2 64

__global__ __launch_bounds__(256, 1)
void mlp_kernel(const float* __restrict__ feat_up,
                const u16*   __restrict__ interp,
                const float* __restrict__ W1, const float* __restrict__ b1,
                const float* __restrict__ g1, const float* __restrict__ be1,
                const float* __restrict__ m1, const float* __restrict__ v1,
                const float* __restrict__ W2, const float* __restrict__ b2,
                const float* __restrict__ g2, const float* __restrict__ be2,
                const float* __restrict__ m2, const float* __restrict__ v2,
                float* __restrict__ out)
{
    __shared__ u16 xb[T2 * 136];
    __shared__ u16 hb[T2 * 136];
    __shared__ u16 w1b[128 * 136];
    __shared__ u16 w2b[64 * 136];
    __shared__ float A1[128], Bc1[128], A2[64], Bc2[64];

    const int tid = threadIdx.x;
    const int b  = blockIdx.x >> 8;
    const int n0 = (blockIdx.x & 255) * T2;
    const int wave = tid >> 6;
    const int lane = tid & 63;
    const int q    = lane >> 4;
    const int nl   = lane & 15;

    if (tid < 128) {
        float a = g1[tid] * rsqrtf(v1[tid] + 1e-5f);
        A1[tid]  = a;
        Bc1[tid] = (b1[tid] - m1[tid]) * a + be1[tid];
    } else if (tid < 192) {
        int o = tid - 128;
        float a = g2[o] * rsqrtf(v2[o] + 1e-5f);
        A2[o]  = a;
        Bc2[o] = (b2[o] - m2[o]) * a + be2[o];
    }
    {
        const float4* src = (const float4*)(W1 + (size_t)(tid >> 1) * 128 + (tid & 1) * 64);
        u16* dst = &w1b[(tid >> 1) * 136 + (tid & 1) * 64];
#pragma unroll
        for (int i = 0; i < 8; i++)
            *(bf16x8*)(dst + 8 * i) = pack8(src[2 * i], src[2 * i + 1]);
    }
    {
        const float4* src = (const float4*)(W2 + (size_t)(tid >> 2) * 128 + (tid & 3) * 32);
        u16* dst = &w2b[(tid >> 2) * 136 + (tid & 3) * 32];
#pragma unroll
        for (int i = 0; i < 4; i++)
            *(bf16x8*)(dst + 8 * i) = pack8(src[2 * i], src[2 * i + 1]);
    }
    if (tid < 128) {
        int n = tid >> 1, hf = tid & 1;
        const float4* src = (const float4*)(feat_up + (size_t)(b * NN + n0 + n) * 64 + hf * 32);
        u16* dst = &xb[n * 136 + hf * 32];
#pragma unroll
        for (int i = 0; i < 4; i++)
            *(bf16x8*)(dst + 8 * i) = pack8(src[2 * i], src[2 * i + 1]);
    } else {
        int t2 = tid - 128;
        int n = t2 >> 1, hf = t2 & 1;
        const uint4* src = (const uint4*)(interp + (size_t)(b * NN + n0 + n) * 64 + hf * 32);
        u16* dst = &xb[n * 136 + 64 + hf * 32];
#pragma unroll
        for (int i = 0; i < 4; i++)
            *(uint4*)(dst + 8 * i) = src[i];
    }
    __syncthreads();

    f32x4 acc1[8];
#pragma unroll
    for (int i = 0; i < 8; i++) acc1[i] = (f32x4){0.f, 0.f, 0.f, 0.f};
#pragma unroll
    for (int k0 = 0; k0 < 128; k0 += 32) {
        bf16x8 a = *(bf16x8*)&xb[(wave * 16 + nl) * 136 + k0 + q * 8];
#pragma unroll
        for (int ot = 0; ot < 8; ot++) {
            bf16x8 bb = *(bf16x8*)&w1b[(ot * 16 + nl) * 136 + k0 + q * 8];
            acc1[ot] = __builtin_amdgcn_mfma_f32_16x16x32_bf16(a, bb, acc1[ot], 0, 0, 0);
        }
    }
#pragma unroll
    for (int ot = 0; ot < 8; ot++) {
        int o = ot * 16 + nl;
        float aa = A1[o], bc = Bc1[o];
#pragma unroll
        for (int reg = 0; reg < 4; reg++) {
            float v = fmaxf(fmaf(acc1[ot][reg], aa, bc), 0.f);
            hb[(wave * 16 + q * 4 + reg) * 136 + o] = f2bf(v);
        }
    }
    __syncthreads();

    f32x4 acc2[4];
#pragma unroll
    for (int i = 0; i < 4; i++) acc2[i] = (f32x4){0.f, 0.f, 0.f, 0.f};
#pragma unroll
    for (int k0 = 0; k0 < 128; k0 += 32) {
        bf16x8 a = *(bf16x8*)&hb[(wave * 16 + nl) * 136 + k0 + q * 8];
#pragma unroll
        for (int ot = 0; ot < 4; ot++) {
            bf16x8 bb = *(bf16x8*)&w2b[(ot * 16 + nl) * 136 + k0 + q * 8];
            acc2[ot] = __builtin_amdgcn_mfma_f32_16x16x32_bf16(a, bb, acc2[ot], 0, 0, 0);
        }
    }
#pragma unroll
    for (int ot = 0; ot < 4; ot++) {
        int o = ot * 16 + nl;
        float aa = A2[o], bc = Bc2[o];
#pragma unroll
        for (int reg = 0; reg < 4; reg++)
            out[(size_t)(b * NN + n0 + wave * 16 + q * 4 + reg) * 64 + o] =
                fmaf(acc2[ot][reg], aa, bc);
    }
}

extern "C" void kernel_launch(void* const* d_in, const int* in_sizes, int n_in,
                              void* d_out, int out_size, void* d_ws, size_t ws_size,
                              hipStream_t stream) {
    const float* xyz_down  = (const float*)d_in[0];
    const float* xyz_up    = (const float*)d_in[1];
    const float* feat_down = (const float*)d_in[2];
    const float* feat_up   = (const float*)d_in[3];
    const float* W1  = (const float*)d_in[4];
    const float* b1  = (const float*)d_in[5];
    const float* g1  = (const float*)d_in[6];
    const float* be1 = (const float*)d_in[7];
    const float* m1  = (const float*)d_in[8];
    const float* v1  = (const float*)d_in[9];
    const float* W2  = (const float*)d_in[10];
    const float* b2  = (const float*)d_in[11];
    const float* g2  = (const float*)d_in[12];
    const float* be2 = (const float*)d_in[13];
    const float* m2  = (const float*)d_in[14];
    const float* v2  = (const float*)d_in[15];
    float* out = (float*)d_out;
    char* ws = (char*)d_ws;

    if (ws_size >= WS_NEED) {
        u16*    fdT   = (u16*)(ws + OFF_FDT);
        float4* xyzP  = (float4*)(ws + OFF_XYZP);
        u16*    w1s   = (u16*)(ws + OFF_W1S);
        u16*    w2s   = (u16*)(ws + OFF_W2S);
        float*  bnbuf = (float*)(ws + OFF_BN);

        prep5_kernel<<<dim3(157), dim3(256), 0, stream>>>(
            xyz_down, feat_down, W1, b1, g1, be1, m1, v1,
            W2, b2, g2, be2, m2, v2, fdT, xyzP, w1s, w2s, bnbuf);
        fused6_kernel<<<dim3(BB * (NN / 64)), dim3(256), 0, stream>>>(
            xyz_up, fdT, xyzP, feat_up, w1s, w2s, bnbuf, out);
    } else {
        u16* interp = (u16*)d_ws;
        interp_kernel<<<dim3(BB * (NN / TN)), dim3(256), 0, stream>>>(
            xyz_down, xyz_up, feat_down, interp);
        mlp_kernel<<<dim3(BB * (NN / T2)), dim3(256), 0, stream>>>(
            feat_up, interp, W1, b1, g1, be1, m1, v1,
            W2, b2, g2, be2, m2, v2, out);
    }
}

// Round 7
// 149.925 us; speedup vs baseline: 1.2074x; 1.2074x over previous
//
#include <hip/hip_runtime.h>

typedef unsigned short u16;
typedef unsigned int   u32;
typedef unsigned long long u64;

typedef __attribute__((ext_vector_type(8))) short bf16x8;
typedef __attribute__((ext_vector_type(4))) float f32x4;
typedef __attribute__((ext_vector_type(2))) float f32x2;

#define BB 4
#define MM 2048
#define NN 16384
#define DD 64

__device__ __forceinline__ u16 f2bf(float f) {
    union { float f; u32 u; } v; v.f = f;
    u32 r = v.u + 0x7fffu + ((v.u >> 16) & 1u);   // RNE
    return (u16)(r >> 16);
}

// pack two floats to bf16 pair by truncation: lo16=trunc(lo), hi16=trunc(hi)
__device__ __forceinline__ u32 pack_trunc(float hi, float lo) {
    union { float f; u32 u; } a, b; a.f = hi; b.f = lo;
    return __builtin_amdgcn_perm(a.u, b.u, 0x07060302);
}

// RNE pack of two floats into a bf16 pair
__device__ __forceinline__ u32 pack_rne(float hi, float lo) {
    return (u32)f2bf(lo) | ((u32)f2bf(hi) << 16);
}

__device__ __forceinline__ bf16x8 pack8(float4 p, float4 q) {
    bf16x8 v;
    v[0] = (short)f2bf(p.x); v[1] = (short)f2bf(p.y);
    v[2] = (short)f2bf(p.z); v[3] = (short)f2bf(p.w);
    v[4] = (short)f2bf(q.x); v[5] = (short)f2bf(q.y);
    v[6] = (short)f2bf(q.z); v[7] = (short)f2bf(q.w);
    return v;
}

// ===========================================================================
// ws layout:
//   [0, 1M)      fdT  bf16 [b][d][m]        (feat_down transposed)
//   [1M, +128K)  xyzP pair-SoA: per pair {-2x0,-2x1,-2y0,-2y1}{-2z0,-2z1,w0,w1}
//   [.., +32K)   w1s  bf16 frag-major [kg*8+ot][lane][8]
//   [.., +16K)   w2s  bf16 frag-major [kg*4+ot][lane][8]
//   [.., +1.5K)  bn consts float[384] = A1[128] Bc1[128] A2[64] Bc2[64]
// ===========================================================================
#define OFF_FDT   0ull
#define OFF_XYZP  1048576ull
#define OFF_W1S   1179648ull
#define OFF_W2S   1212416ull
#define OFF_BN    1228800ull
#define WS_NEED   1230336ull

// ---------------------------------------------------------------------------
// prep6: 285 blocks x 256.
//  blk   0..255 : feat_down transpose (b = blk>>6, 32-m tile = blk&63)
//  blk 256..271 : xyzP pair-SoA
//  blk 272..279 : W1 -> bf16 frag-major
//  blk 280..283 : W2 -> bf16 frag-major
//  blk 284      : BN fold
// ---------------------------------------------------------------------------
__global__ __launch_bounds__(256)
void prep6_kernel(const float* __restrict__ xyz_down,
                  const float* __restrict__ feat_down,
                  const float* __restrict__ W1, const float* __restrict__ b1,
                  const float* __restrict__ g1, const float* __restrict__ be1,
                  const float* __restrict__ m1, const float* __restrict__ v1,
                  const float* __restrict__ W2, const float* __restrict__ b2,
                  const float* __restrict__ g2, const float* __restrict__ be2,
                  const float* __restrict__ m2, const float* __restrict__ v2,
                  u16* __restrict__ fdT, float4* __restrict__ xyzP,
                  u16* __restrict__ w1s, u16* __restrict__ w2s,
                  float* __restrict__ bnbuf)
{
    const int blk = blockIdx.x, t = threadIdx.x;
    if (blk < 256) {
        __shared__ u16 T[32 * 72];                 // [m_local][d], stride 72 (144B, 16B-aligned)
        const int b = blk >> 6, m0 = (blk & 63) * 32;
        // phase A: coalesced read, convert, 16B-aligned uint4 LDS writes
        {
            const int row = t >> 3, seg = (t & 7) * 8;   // 8 threads/row, 8 cols each
            const float4* src = (const float4*)(feat_down + ((size_t)(b * MM + m0 + row)) * 64 + seg);
            float4 v0 = src[0], v1 = src[1];
            bf16x8 pk = pack8(v0, v1);
            *(bf16x8*)&T[row * 72 + seg] = pk;
        }
        __syncthreads();
        // phase B: per wave d = t&63 (2-way banks = free), 8 m's per thread
        {
            const int d = t & 63, w = t >> 6;
            union { u16 h[8]; uint4 q; } o;
#pragma unroll
            for (int j = 0; j < 8; j++) o.h[j] = T[(w * 8 + j) * 72 + d];
            *(uint4*)&fdT[((size_t)(b * 64 + d)) * MM + m0 + w * 8] = o.q;
        }
    } else if (blk < 272) {
        int g = (blk - 256) * 256 + t;             // pair index over 4096
        int b = g >> 10, p = g & 1023;
        const float* s = xyz_down + ((size_t)b * MM + 2 * p) * 3;
        float x0 = s[0], y0 = s[1], z0 = s[2];
        float x1 = s[3], y1 = s[4], z1 = s[5];
        float w0 = x0 * x0 + y0 * y0 + z0 * z0 + 1e-8f;
        float w1v = x1 * x1 + y1 * y1 + z1 * z1 + 1e-8f;
        xyzP[(size_t)g * 2 + 0] = make_float4(-2.f * x0, -2.f * x1, -2.f * y0, -2.f * y1);
        xyzP[(size_t)g * 2 + 1] = make_float4(-2.f * z0, -2.f * z1, w0, w1v);
    } else if (blk < 280) {
        int slot = (blk - 272) * 256 + t;          // 0..2047
        int f = slot >> 6, l = slot & 63;
        int kg = f >> 3, ot = f & 7;
        int o = ot * 16 + (l & 15), c = kg * 32 + (l >> 4) * 8;
        const float4* src = (const float4*)(W1 + (size_t)o * 128 + c);
        bf16x8 v = pack8(src[0], src[1]);
        *(bf16x8*)&w1s[(size_t)slot * 8] = v;
    } else if (blk < 284) {
        int slot = (blk - 280) * 256 + t;          // 0..1023
        int f = slot >> 6, l = slot & 63;
        int kg = f >> 2, ot = f & 3;
        int o = ot * 16 + (l & 15), c = kg * 32 + (l >> 4) * 8;
        const float4* src = (const float4*)(W2 + (size_t)o * 128 + c);
        bf16x8 v = pack8(src[0], src[1]);
        *(bf16x8*)&w2s[(size_t)slot * 8] = v;
    } else {
        if (t < 128) {
            float a = g1[t] * rsqrtf(v1[t] + 1e-5f);
            bnbuf[t] = a;
            bnbuf[128 + t] = (b1[t] - m1[t]) * a + be1[t];
        } else if (t < 192) {
            int o = t - 128;
            float a = g2[o] * rsqrtf(v2[o] + 1e-5f);
            bnbuf[256 + o] = a;
            bnbuf[320 + o] = (b2[o] - m2[o]) * a + be2[o];
        }
    }
}

// ---------------------------------------------------------------------------
// fused7: 128 n-rows/block (2 row-tiles per wave -> xyz LDS reads amortized
// 2x), interp4-style single-barrier LDS double-buffer (ftbuf + pair-SoA xyz),
// packed fp32 dist, den via MFMA-ones, fused MLP with frag-major global
// weights. All MLP LDS handoffs wave-private (32-row slabs) -> no extra
// barriers. 512 blocks x 256; LDS 57.9 KB -> 2 blocks/CU (one pass).
// ---------------------------------------------------------------------------
__global__ __launch_bounds__(256, 2)
void fused7_kernel(const float* __restrict__ xyz_up,
                   const u16* __restrict__ fdT,
                   const float4* __restrict__ xyzP,
                   const float* __restrict__ feat_up,
                   const u16* __restrict__ w1s,
                   const u16* __restrict__ w2s,
                   const float* __restrict__ bnbuf,
                   float* __restrict__ out)
{
    __shared__ u16   ftbuf[2][64 * 72];   // 18432 B  feat^T chunk [d][m]
    __shared__ float xyzb[2][32 * 12];    //  3072 B  pair-SoA, 48B/pair stride
    __shared__ u16   xh[128 * 136];       // 34816 B  x -> h -> f32 out (68 dw)
    __shared__ float bnl[384];            //  1536 B

    const int tid = threadIdx.x;
    const int b  = blockIdx.x >> 7;
    const int n0 = (blockIdx.x & 127) * 128;
    const int wave = tid >> 6;
    const int lane = tid & 63;
    const int q    = lane >> 4;
    const int nl   = lane & 15;

    bnl[tid] = bnbuf[tid];
    if (tid < 128) bnl[256 + tid] = bnbuf[256 + tid];

    // stage feat_up -> xh cols 0..63 (wave-private rows: tid>>1 in
    // [wave*32, wave*32+32))
    {
        const int r = tid >> 1, sg = (tid & 1) * 32;   // 32 floats each
        const float4* fs = (const float4*)(feat_up + ((size_t)(b * NN + n0 + r)) * 64 + sg);
        float4 f0 = fs[0], f1 = fs[1], f2 = fs[2], f3 = fs[3];
        float4 f4 = fs[4], f5 = fs[5], f6 = fs[6], f7 = fs[7];
        uint4 o0, o1;
        o0.x = pack_rne(f0.y, f0.x); o0.y = pack_rne(f0.w, f0.z);
        o0.z = pack_rne(f1.y, f1.x); o0.w = pack_rne(f1.w, f1.z);
        o1.x = pack_rne(f2.y, f2.x); o1.y = pack_rne(f2.w, f2.z);
        o1.z = pack_rne(f3.y, f3.x); o1.w = pack_rne(f3.w, f3.z);
        uint4* xd = (uint4*)&xh[r * 136 + sg];
        xd[0] = o0; xd[1] = o1;
        uint4 o2, o3;
        o2.x = pack_rne(f4.y, f4.x); o2.y = pack_rne(f4.w, f4.z);
        o2.z = pack_rne(f5.y, f5.x); o2.w = pack_rne(f5.w, f5.z);
        o3.x = pack_rne(f6.y, f6.x); o3.y = pack_rne(f6.w, f6.z);
        o3.z = pack_rne(f7.y, f7.x); o3.w = pack_rne(f7.w, f7.z);
        xd[2] = o2; xd[3] = o3;
    }

    // ---------------- interp phase ----------------
    // wave owns rows wave*32 .. wave*32+31 (2 row-tiles of 16)
    float ax[2], ay[2], az[2];
    f32x2 a22[2];
#pragma unroll
    for (int rt = 0; rt < 2; rt++) {
        const int row = n0 + wave * 32 + rt * 16 + nl;
        const float* xu = xyz_up + ((size_t)(b * NN + row)) * 3;
        ax[rt] = xu[0]; ay[rt] = xu[1]; az[rt] = xu[2];
        float a2 = ax[rt] * ax[rt] + ay[rt] * ay[rt] + az[rt] * az[rt];
        a22[rt] = (f32x2){a2, a2};
    }
    const f32x2 eps2 = (f32x2){1e-8f, 1e-8f};

    f32x4 acc[2][4];
#pragma unroll
    for (int rt = 0; rt < 2; rt++)
#pragma unroll
        for (int i = 0; i < 4; i++) acc[rt][i] = (f32x4){0.f, 0.f, 0.f, 0.f};
    f32x4 accd[2];
    accd[0] = (f32x4){0.f, 0.f, 0.f, 0.f};
    accd[1] = (f32x4){0.f, 0.f, 0.f, 0.f};

    bf16x8 ones;
#pragma unroll
    for (int i = 0; i < 8; i++) ones[i] = (short)0x3F80;   // bf16 1.0

    // ftbuf staging identity: d = tid>>2, 32B of m
    const int sd = tid >> 2, sms = (tid & 3) * 16;
    const u16* fsrc = fdT + ((size_t)(b * 64 + sd)) * MM + sms;
    // xyzb staging identity (tid<64): pair = tid>>1, half = tid&1
    const float4* xsrc = xyzP + ((size_t)b * 1024 + (tid >> 1)) * 2 + (tid & 1);
    float* xdst = &xyzb[0][0] + (tid >> 1) * 12 + (tid & 1) * 4;

    {   // prologue: stage chunk 0
        u16* fd = &ftbuf[0][sd * 72 + sms];
        *(uint4*)fd       = *(const uint4*)(fsrc);
        *(uint4*)(fd + 8) = *(const uint4*)(fsrc + 8);
        if (tid < 64) *(float4*)xdst = xsrc[0];
    }
    __syncthreads();

    for (int c = 0; c < 32; ++c) {
        const int cur = c & 1, nxt = cur ^ 1;
        const bool have_next = (c + 1) < 32;
        uint4 nf0, nf1; float4 nx;
        if (have_next) {
            const int mc = (c + 1) * 64;
            nf0 = *(const uint4*)(fsrc + mc);
            nf1 = *(const uint4*)(fsrc + mc + 8);
            if (tid < 64) nx = xsrc[(size_t)(c + 1) * 64];   // 32 pairs * 2 float4
        }

#pragma unroll
        for (int kk = 0; kk < 2; kk++) {
            u32 fr[2][4];
#pragma unroll
            for (int jp = 0; jp < 4; jp++) {
                const int pi = kk * 16 + q * 4 + jp;       // pair in chunk
                const float* base = &xyzb[cur][pi * 12];
                float4 ld0 = *(const float4*)(base);       // {-2x0,-2x1,-2y0,-2y1}
                float4 ld1 = *(const float4*)(base + 4);   // {-2z0,-2z1, w0, w1}
                f32x2 px = (f32x2){ld0.x, ld0.y};
                f32x2 py = (f32x2){ld0.z, ld0.w};
                f32x2 pz = (f32x2){ld1.x, ld1.y};
                f32x2 pw = (f32x2){ld1.z, ld1.w};
#pragma unroll
                for (int rt = 0; rt < 2; rt++) {
                    f32x2 d = __builtin_elementwise_fma(px, (f32x2){ax[rt], ax[rt]},
                              __builtin_elementwise_fma(py, (f32x2){ay[rt], ay[rt]},
                              __builtin_elementwise_fma(pz, (f32x2){az[rt], az[rt]},
                                                        pw + a22[rt])));
                    d = __builtin_elementwise_max(d, eps2);
                    float r0 = __builtin_amdgcn_rcpf(d.x);
                    float r1 = __builtin_amdgcn_rcpf(d.y);
                    fr[rt][jp] = pack_trunc(r1, r0);
                }
            }
            // B-frags once, reused by both row-tiles
            bf16x8 bb[4];
#pragma unroll
            for (int dt = 0; dt < 4; dt++)
                bb[dt] = *(bf16x8*)&ftbuf[cur][(dt * 16 + nl) * 72 + kk * 32 + q * 8];
#pragma unroll
            for (int rt = 0; rt < 2; rt++) {
                union { u32 u[4]; bf16x8 v; } af;
                af.u[0] = fr[rt][0]; af.u[1] = fr[rt][1];
                af.u[2] = fr[rt][2]; af.u[3] = fr[rt][3];
#pragma unroll
                for (int dt = 0; dt < 4; dt++)
                    acc[rt][dt] = __builtin_amdgcn_mfma_f32_16x16x32_bf16(af.v, bb[dt], acc[rt][dt], 0, 0, 0);
                accd[rt] = __builtin_amdgcn_mfma_f32_16x16x32_bf16(af.v, ones, accd[rt], 0, 0, 0);
            }
        }

        if (have_next) {
            u16* fd = &ftbuf[nxt][sd * 72 + sms];
            *(uint4*)fd       = nf0;
            *(uint4*)(fd + 8) = nf1;
            if (tid < 64) *(float4*)(&xyzb[nxt][0] + (tid >> 1) * 12 + (tid & 1) * 4) = nx;
        }
        __syncthreads();
    }

    // interp epilogue: normalize, write bf16 to xh cols 64..127 (wave-private rows)
#pragma unroll
    for (int rt = 0; rt < 2; rt++)
#pragma unroll
    for (int reg = 0; reg < 4; reg++) {
        float inv = 1.0f / accd[rt][reg];
        int rl = wave * 32 + rt * 16 + q * 4 + reg;
#pragma unroll
        for (int dt = 0; dt < 4; dt++)
            xh[rl * 136 + 64 + dt * 16 + nl] = f2bf(acc[rt][dt][reg] * inv);
    }
    // no barrier: MLP reads are wave-private rows; in-wave LDS order is HW-guaranteed

    // ---------------- GEMM1: x(128x128) @ W1^T -> h ----------------
    f32x4 acc1[2][8];
#pragma unroll
    for (int rt = 0; rt < 2; rt++)
#pragma unroll
        for (int i = 0; i < 8; i++) acc1[rt][i] = (f32x4){0.f, 0.f, 0.f, 0.f};
#pragma unroll
    for (int kg = 0; kg < 4; kg++) {
        bf16x8 afr[2];
#pragma unroll
        for (int rt = 0; rt < 2; rt++)
            afr[rt] = *(bf16x8*)&xh[(wave * 32 + rt * 16 + nl) * 136 + kg * 32 + q * 8];
#pragma unroll
        for (int ot = 0; ot < 8; ot++) {
            bf16x8 bf = *(const bf16x8*)(w1s + ((size_t)(kg * 8 + ot) * 64 + lane) * 8);
            acc1[0][ot] = __builtin_amdgcn_mfma_f32_16x16x32_bf16(afr[0], bf, acc1[0][ot], 0, 0, 0);
            acc1[1][ot] = __builtin_amdgcn_mfma_f32_16x16x32_bf16(afr[1], bf, acc1[1][ot], 0, 0, 0);
        }
    }
    // BN1 + ReLU -> bf16 h into xh (wave-private rows)
#pragma unroll
    for (int ot = 0; ot < 8; ot++) {
        int o = ot * 16 + nl;
        float aa = bnl[o], bc = bnl[128 + o];
#pragma unroll
        for (int rt = 0; rt < 2; rt++)
#pragma unroll
        for (int reg = 0; reg < 4; reg++) {
            float v = fmaxf(fmaf(acc1[rt][ot][reg], aa, bc), 0.f);
            xh[(wave * 32 + rt * 16 + q * 4 + reg) * 136 + o] = f2bf(v);
        }
    }

    // ---------------- GEMM2: h(128x128) @ W2^T -> out ----------------
    f32x4 acc2[2][4];
#pragma unroll
    for (int rt = 0; rt < 2; rt++)
#pragma unroll
        for (int i = 0; i < 4; i++) acc2[rt][i] = (f32x4){0.f, 0.f, 0.f, 0.f};
#pragma unroll
    for (int kg = 0; kg < 4; kg++) {
        bf16x8 afr[2];
#pragma unroll
        for (int rt = 0; rt < 2; rt++)
            afr[rt] = *(bf16x8*)&xh[(wave * 32 + rt * 16 + nl) * 136 + kg * 32 + q * 8];
#pragma unroll
        for (int ot = 0; ot < 4; ot++) {
            bf16x8 bf = *(const bf16x8*)(w2s + ((size_t)(kg * 4 + ot) * 64 + lane) * 8);
            acc2[0][ot] = __builtin_amdgcn_mfma_f32_16x16x32_bf16(afr[0], bf, acc2[0][ot], 0, 0, 0);
            acc2[1][ot] = __builtin_amdgcn_mfma_f32_16x16x32_bf16(afr[1], bf, acc2[1][ot], 0, 0, 0);
        }
    }
    // BN2 -> f32 tile in xh (float view, 68-dword rows, wave-private)
    float* of = (float*)xh;
#pragma unroll
    for (int ot = 0; ot < 4; ot++) {
        int o = ot * 16 + nl;
        float aa = bnl[256 + o], bc = bnl[320 + o];
#pragma unroll
        for (int rt = 0; rt < 2; rt++)
#pragma unroll
        for (int reg = 0; reg < 4; reg++)
            of[(wave * 32 + rt * 16 + q * 4 + reg) * 68 + o] = fmaf(acc2[rt][ot][reg], aa, bc);
    }

    // coalesced out store (wave-private rows: tid>>1 in [wave*32, wave*32+32))
    {
        const int r = tid >> 1, sg = (tid & 1) * 32;
        const float4* sf = (const float4*)&of[r * 68 + sg];
        float4* dst = (float4*)(out + ((size_t)(b * NN + n0 + r)) * 64 + sg);
#pragma unroll
        for (int i = 0; i < 8; i++) dst[i] = sf[i];
    }
}

// ===========================================================================
// Fallback (round-1 kernels, proven): used when ws_size < WS_NEED.
// ===========================================================================
#define TN 128
#define BM 64
#define RS 72
#define FS 72

__global__ __launch_bounds__(256, 3)
void interp_kernel(const float* __restrict__ xyz_down,
                   const float* __restrict__ xyz_up,
                   const float* __restrict__ feat_down,
                   u16* __restrict__ interp_out)
{
    __shared__ u16   rbuf[TN * RS];
    __shared__ u16   ftbuf[DD * FS];
    __shared__ float xyzb[BM * 3];
    __shared__ float denp[TN * 2];
    __shared__ float invden[TN];

    const int tid = threadIdx.x;
    const int b  = blockIdx.x >> 7;
    const int n0 = (blockIdx.x & 127) * TN;

    const int nl_r = tid >> 1;
    const int half = tid & 1;
    const float* xu = xyz_up + (size_t)(b * NN + n0 + nl_r) * 3;
    const float ax = xu[0], ay = xu[1], az = xu[2];

    denp[tid] = 0.f;

    const int wave = tid >> 6;
    const int lane = tid & 63;
    const int q    = lane >> 4;
    const int nl   = lane & 15;

    f32x4 acc[2][4];
#pragma unroll
    for (int i = 0; i < 2; i++)
#pragma unroll
        for (int j = 0; j < 4; j++) acc[i][j] = (f32x4){0.f, 0.f, 0.f, 0.f};

    const int sm = (tid & 31) * 2;
    const int sd = (tid >> 5) * 8;

    for (int mc = 0; mc < MM; mc += BM) {
        __syncthreads();
        if (tid < 192) xyzb[tid] = xyz_down[(size_t)(b * MM + mc) * 3 + tid];
        {
            const float4* f0 = (const float4*)(feat_down + (size_t)(b * MM + mc + sm) * DD + sd);
            const float4* f1 = (const float4*)(feat_down + (size_t)(b * MM + mc + sm + 1) * DD + sd);
            float4 a0 = f0[0], a1 = f0[1];
            float4 b0 = f1[0], b1 = f1[1];
            float r0[8] = {a0.x, a0.y, a0.z, a0.w, a1.x, a1.y, a1.z, a1.w};
            float r1[8] = {b0.x, b0.y, b0.z, b0.w, b1.x, b1.y, b1.z, b1.w};
#pragma unroll
            for (int j = 0; j < 8; j++) {
                u32 pk = (u32)f2bf(r0[j]) | ((u32)f2bf(r1[j]) << 16);
                *(u32*)&ftbuf[(sd + j) * FS + sm] = pk;
            }
        }
        __syncthreads();
        {
            float dlc = 0.f;
#pragma unroll
            for (int s = 0; s < 4; s++) {
                bf16x8 v;
#pragma unroll
                for (int j = 0; j < 8; j++) {
                    int m = half * 32 + s * 8 + j;
                    float dx = ax - xyzb[3 * m + 0];
                    float dy = ay - xyzb[3 * m + 1];
                    float dz = az - xyzb[3 * m + 2];
                    float d = fmaf(dx, dx, fmaf(dy, dy, dz * dz)) + 1e-8f;
                    float r = __builtin_amdgcn_rcpf(d);
                    dlc += r;
                    v[j] = (short)f2bf(r);
                }
                *(bf16x8*)&rbuf[nl_r * RS + half * 32 + s * 8] = v;
            }
            denp[nl_r * 2 + half] += dlc;
        }
        __syncthreads();
        {
            const int rowbase = wave * 32;
#pragma unroll
            for (int k0 = 0; k0 < BM; k0 += 32) {
                bf16x8 a0 = *(bf16x8*)&rbuf[(rowbase + nl) * RS + k0 + q * 8];
                bf16x8 a1 = *(bf16x8*)&rbuf[(rowbase + 16 + nl) * RS + k0 + q * 8];
#pragma unroll
                for (int dt = 0; dt < 4; dt++) {
                    bf16x8 bb = *(bf16x8*)&ftbuf[(dt * 16 + nl) * FS + k0 + q * 8];
                    acc[0][dt] = __builtin_amdgcn_mfma_f32_16x16x32_bf16(a0, bb, acc[0][dt], 0, 0, 0);
                    acc[1][dt] = __builtin_amdgcn_mfma_f32_16x16x32_bf16(a1, bb, acc[1][dt], 0, 0, 0);
                }
            }
        }
    }

    __syncthreads();
    if (tid < TN) invden[tid] = 1.0f / (denp[tid * 2] + denp[tid * 2 + 1]);
    __syncthreads();
    {
        const int rowbase = wave * 32;
#pragma unroll
        for (int nt = 0; nt < 2; nt++) {
#pragma unroll
            for (int reg = 0; reg < 4; reg++) {
                int nloc = rowbase + nt * 16 + q * 4 + reg;
                float inv = invden[nloc];
                size_t gbase = (size_t)(b * NN + n0 + nloc) * DD;
#pragma unroll
                for (int dt = 0; dt < 4; dt++)
                    interp_out[gbase + dt * 16 + nl] = f2bf(acc[nt][dt][reg] * inv);
            }
        }
    }
}

#define T2 64

__global__ __launch_bounds__(256, 1)
void mlp_kernel(const float* __restrict__ feat_up,
                const u16*   __restrict__ interp,
                const float* __restrict__ W1, const float* __restrict__ b1,
                const float* __restrict__ g1, const float* __restrict__ be1,
                const float* __restrict__ m1, const float* __restrict__ v1,
                const float* __restrict__ W2, const float* __restrict__ b2,
                const float* __restrict__ g2, const float* __restrict__ be2,
                const float* __restrict__ m2, const float* __restrict__ v2,
                float* __restrict__ out)
{
    __shared__ u16 xb[T2 * 136];
    __shared__ u16 hb[T2 * 136];
    __shared__ u16 w1b[128 * 136];
    __shared__ u16 w2b[64 * 136];
    __shared__ float A1[128], Bc1[128], A2[64], Bc2[64];

    const int tid = threadIdx.x;
    const int b  = blockIdx.x >> 8;
    const int n0 = (blockIdx.x & 255) * T2;
    const int wave = tid >> 6;
    const int lane = tid & 63;
    const int q    = lane >> 4;
    const int nl   = lane & 15;

    if (tid < 128) {
        float a = g1[tid] * rsqrtf(v1[tid] + 1e-5f);
        A1[tid]  = a;
        Bc1[tid] = (b1[tid] - m1[tid]) * a + be1[tid];
    } else if (tid < 192) {
        int o = tid - 128;
        float a = g2[o] * rsqrtf(v2[o] + 1e-5f);
        A2[o]  = a;
        Bc2[o] = (b2[o] - m2[o]) * a + be2[o];
    }
    {
        const float4* src = (const float4*)(W1 + (size_t)(tid >> 1) * 128 + (tid & 1) * 64);
        u16* dst = &w1b[(tid >> 1) * 136 + (tid & 1) * 64];
#pragma unroll
        for (int i = 0; i < 8; i++)
            *(bf16x8*)(dst + 8 * i) = pack8(src[2 * i], src[2 * i + 1]);
    }
    {
        const float4* src = (const float4*)(W2 + (size_t)(tid >> 2) * 128 + (tid & 3) * 32);
        u16* dst = &w2b[(tid >> 2) * 136 + (tid & 3) * 32];
#pragma unroll
        for (int i = 0; i < 4; i++)
            *(bf16x8*)(dst + 8 * i) = pack8(src[2 * i], src[2 * i + 1]);
    }
    if (tid < 128) {
        int n = tid >> 1, hf = tid & 1;
        const float4* src = (const float4*)(feat_up + (size_t)(b * NN + n0 + n) * 64 + hf * 32);
        u16* dst = &xb[n * 136 + hf * 32];
#pragma unroll
        for (int i = 0; i < 4; i++)
            *(bf16x8*)(dst + 8 * i) = pack8(src[2 * i], src[2 * i + 1]);
    } else {
        int t2 = tid - 128;
        int n = t2 >> 1, hf = t2 & 1;
        const uint4* src = (const uint4*)(interp + (size_t)(b * NN + n0 + n) * 64 + hf * 32);
        u16* dst = &xb[n * 136 + 64 + hf * 32];
#pragma unroll
        for (int i = 0; i < 4; i++)
            *(uint4*)(dst + 8 * i) = src[i];
    }
    __syncthreads();

    f32x4 acc1[8];
#pragma unroll
    for (int i = 0; i < 8; i++) acc1[i] = (f32x4){0.f, 0.f, 0.f, 0.f};
#pragma unroll
    for (int k0 = 0; k0 < 128; k0 += 32) {
        bf16x8 a = *(bf16x8*)&xb[(wave * 16 + nl) * 136 + k0 + q * 8];
#pragma unroll
        for (int ot = 0; ot < 8; ot++) {
            bf16x8 bb = *(bf16x8*)&w1b[(ot * 16 + nl) * 136 + k0 + q * 8];
            acc1[ot] = __builtin_amdgcn_mfma_f32_16x16x32_bf16(a, bb, acc1[ot], 0, 0, 0);
        }
    }
#pragma unroll
    for (int ot = 0; ot < 8; ot++) {
        int o = ot * 16 + nl;
        float aa = A1[o], bc = Bc1[o];
#pragma unroll
        for (int reg = 0; reg < 4; reg++) {
            float v = fmaxf(fmaf(acc1[ot][reg], aa, bc), 0.f);
            hb[(wave * 16 + q * 4 + reg) * 136 + o] = f2bf(v);
        }
    }
    __syncthreads();

    f32x4 acc2[4];
#pragma unroll
    for (int i = 0; i < 4; i++) acc2[i] = (f32x4){0.f, 0.f, 0.f, 0.f};
#pragma unroll
    for (int k0 = 0; k0 < 128; k0 += 32) {
        bf16x8 a = *(bf16x8*)&hb[(wave * 16 + nl) * 136 + k0 + q * 8];
#pragma unroll
        for (int ot = 0; ot < 4; ot++) {
            bf16x8 bb = *(bf16x8*)&w2b[(ot * 16 + nl) * 136 + k0 + q * 8];
            acc2[ot] = __builtin_amdgcn_mfma_f32_16x16x32_bf16(a, bb, acc2[ot], 0, 0, 0);
        }
    }
#pragma unroll
    for (int ot = 0; ot < 4; ot++) {
        int o = ot * 16 + nl;
        float aa = A2[o], bc = Bc2[o];
#pragma unroll
        for (int reg = 0; reg < 4; reg++)
            out[(size_t)(b * NN + n0 + wave * 16 + q * 4 + reg) * 64 + o] =
                fmaf(acc2[ot][reg], aa, bc);
    }
}

extern "C" void kernel_launch(void* const* d_in, const int* in_sizes, int n_in,
                              void* d_out, int out_size, void* d_ws, size_t ws_size,
                              hipStream_t stream) {
    const float* xyz_down  = (const float*)d_in[0];
    const float* xyz_up    = (const float*)d_in[1];
    const float* feat_down = (const float*)d_in[2];
    const float* feat_up   = (const float*)d_in[3];
    const float* W1  = (const float*)d_in[4];
    const float* b1  = (const float*)d_in[5];
    const float* g1  = (const float*)d_in[6];
    const float* be1 = (const float*)d_in[7];
    const float* m1  = (const float*)d_in[8];
    const float* v1  = (const float*)d_in[9];
    const float* W2  = (const float*)d_in[10];
    const float* b2  = (const float*)d_in[11];
    const float* g2  = (const float*)d_in[12];
    const float* be2 = (const float*)d_in[13];
    const float* m2  = (const float*)d_in[14];
    const float* v2  = (const float*)d_in[15];
    float* out = (float*)d_out;
    char* ws = (char*)d_ws;

    if (ws_size >= WS_NEED) {
        u16*    fdT   = (u16*)(ws + OFF_FDT);
        float4* xyzP  = (float4*)(ws + OFF_XYZP);
        u16*    w1s   = (u16*)(ws + OFF_W1S);
        u16*    w2s   = (u16*)(ws + OFF_W2S);
        float*  bnbuf = (float*)(ws + OFF_BN);

        prep6_kernel<<<dim3(285), dim3(256), 0, stream>>>(
            xyz_down, feat_down, W1, b1, g1, be1, m1, v1,
            W2, b2, g2, be2, m2, v2, fdT, xyzP, w1s, w2s, bnbuf);
        fused7_kernel<<<dim3(BB * (NN / 128)), dim3(256), 0, stream>>>(
            xyz_up, fdT, xyzP, feat_up, w1s, w2s, bnbuf, out);
    } else {
        u16* interp = (u16*)d_ws;
        interp_kernel<<<dim3(BB * (NN / TN)), dim3(256), 0, stream>>>(
            xyz_down, xyz_up, feat_down, interp);
        mlp_kernel<<<dim3(BB * (NN / T2)), dim3(256), 0, stream>>>(
            feat_up, interp, W1, b1, g1, be1, m1, v1,
            W2, b2, g2, be2, m2, v2, out);
    }
}